// Round 2
// baseline (324470.972 us; speedup 1.0000x reference)
//
#include <hip/hip_runtime.h>
#include <hip/hip_cooperative_groups.h>
#include <math.h>

namespace cg = cooperative_groups;

// ============================================================
// Tacotron2 decoder. Round 2: persistent cooperative decode loop.
// B=64, T_ENC=512, T_DEC=500, MEL=80, PRE=256, ENC_D=512, H=1024, ATT=128
//  - prolog: k_prep (transposes/fused consts/zero), k_prenet, k_memT (mem^T)
//  - k_decode: ONE cooperative kernel, 256 blocks x 256 thr, 500 steps,
//    4 grid syncs/step:  P1 q+energy | P2 softmax+ctx+heads | P3 gates0 | P4 gates1
//  - epilog: 5-layer conv postnet (unchanged from R1, which passed)
// ============================================================

// ---------------- ws layout (float offsets) ----------------
static constexpr long OFF_P1WT = 0;                        // [80][256]
static constexpr long OFF_P2WT = OFF_P1WT + 20480;         // [256][256]
static constexpr long OFF_MWT  = OFF_P2WT + 65536;         // [1536][80]
static constexpr long OFF_AQT  = OFF_MWT  + 122880;        // [1024][128]
static constexpr long OFF_WLOC = OFF_AQT  + 131072;        // [128][32]
static constexpr long OFF_BLOC = OFF_WLOC + 4096;          // [128]
static constexpr long OFF_GB0  = OFF_BLOC + 128;           // [4096]
static constexpr long OFF_GB1  = OFF_GB0  + 4096;          // [4096]
static constexpr long OFF_PWT0 = OFF_GB1  + 4096;          // [400][512]
static constexpr long OFF_PWT1 = OFF_PWT0 + 204800;        // [2560][512]
static constexpr long OFF_PWT2 = OFF_PWT1 + 1310720;
static constexpr long OFF_PWT3 = OFF_PWT2 + 1310720;
static constexpr long OFF_PWT4 = OFF_PWT3 + 1310720;       // [2560][80]
static constexpr long OFF_PRE  = OFF_PWT4 + 204800;        // [500*64][256]
static constexpr long OFF_MEM  = OFF_PRE  + 500L*64*256;   // mem^T [64][128][512]
static constexpr long OFF_H0   = OFF_MEM  + 64L*128*512;   // 2 x [64][1024]  -- zero start
static constexpr long OFF_H1   = OFF_H0   + 131072;        // 2 x [64][1024]
static constexpr long OFF_C0   = OFF_H1   + 131072;        // [64][1024]
static constexpr long OFF_C1   = OFF_C0   + 65536;         // [64][1024]     -- zero end
static constexpr long OFF_CTX  = OFF_C1   + 65536;         // 2 x [64][512]
static constexpr long OFF_EBUF = OFF_CTX  + 65536;         // [64][512]
static constexpr long OFF_PB0  = OFF_EBUF + 32768;         // postnet [64][512][500]
static constexpr long OFF_PB1  = OFF_PB0  + 16384000;

// d_out layout: [mel+post | mel | stop | attw]
static constexpr long DO_MEL  = 64L*500*80;
static constexpr long DO_STOP = 2*DO_MEL;
static constexpr long DO_ATT  = DO_STOP + 64L*500;

static constexpr long ZERO_CNT = 6L*65536;                 // 393216
static constexpr long PREP_TOTAL = ZERO_CNT + 4096 + 4096 + 4096 + 128
  + 20480 + 65536 + 122880 + 131072
  + 204800 + 1310720 + 1310720 + 1310720 + 204800;         // 5,087,360

__device__ __forceinline__ float fsigmoid(float x) { return 1.f / (1.f + __expf(-x)); }
__device__ __forceinline__ float ftanh(float x) {
  float ax = fminf(fabsf(x), 15.f);
  float e = __expf(-2.f * ax);
  float r = (1.f - e) / (1.f + e);
  return copysignf(r, x);
}

// ---------------- prolog: transposes / fused constants / zero-init ----------------
__global__ __launch_bounds__(256) void k_prep(
    const float* __restrict__ bih0, const float* __restrict__ bhh0,
    const float* __restrict__ bih1, const float* __restrict__ bhh1,
    const float* __restrict__ al,   const float* __restrict__ alcw,
    const float* __restrict__ alcb, const float* __restrict__ ab,
    const float* __restrict__ p1w,  const float* __restrict__ p2w,
    const float* __restrict__ mw,   const float* __restrict__ aq,
    const float* __restrict__ pw0, const float* __restrict__ pw1,
    const float* __restrict__ pw2, const float* __restrict__ pw3,
    const float* __restrict__ pw4,
    float* __restrict__ ws)
{
  long stride = (long)gridDim.x * 256;
  for (long idx = (long)blockIdx.x * 256 + threadIdx.x; idx < PREP_TOTAL; idx += stride) {
    long r = idx;
    if (r < ZERO_CNT) { ws[OFF_H0 + r] = 0.f; continue; }
    r -= ZERO_CNT;
    if (r < 4096) { ws[OFF_GB0 + r] = bih0[r] + bhh0[r]; continue; }
    r -= 4096;
    if (r < 4096) { ws[OFF_GB1 + r] = bih1[r] + bhh1[r]; continue; }
    r -= 4096;
    if (r < 4096) {   // W_loc[a][k] = sum_c al[a,c]*alcw[c,0,k]
      int a = (int)(r >> 5), k = (int)(r & 31);
      float v = 0.f;
      if (k < 31) for (int ch = 0; ch < 32; ++ch) v += al[a*32 + ch] * alcw[ch*31 + k];
      ws[OFF_WLOC + r] = v; continue;
    }
    r -= 4096;
    if (r < 128) {    // bloc[a] = sum_c al[a,c]*alcb[c] + ab[a]
      float v = ab[r];
      for (int ch = 0; ch < 32; ++ch) v += al[r*32 + ch] * alcb[ch];
      ws[OFF_BLOC + r] = v; continue;
    }
    r -= 128;
    if (r < 20480) { int k = (int)(r >> 8), j = (int)(r & 255); ws[OFF_P1WT + r] = p1w[j*80 + k]; continue; }
    r -= 20480;
    if (r < 65536) { int k = (int)(r >> 8), j = (int)(r & 255); ws[OFF_P2WT + r] = p2w[j*256 + k]; continue; }
    r -= 65536;
    if (r < 122880) { int k = (int)(r / 80), c = (int)(r % 80); ws[OFF_MWT + r] = mw[(long)c*1536 + k]; continue; }
    r -= 122880;
    if (r < 131072) { int k = (int)(r >> 7), a2 = (int)(r & 127); ws[OFF_AQT + r] = aq[(long)a2*1024 + k]; continue; }
    r -= 131072;
    if (r < 204800) { int c5 = (int)(r / 512), co = (int)(r % 512); ws[OFF_PWT0 + r] = pw0[((long)co*80  + c5/5)*5 + (c5%5)]; continue; }
    r -= 204800;
    if (r < 1310720) { int c5 = (int)(r / 512), co = (int)(r % 512); ws[OFF_PWT1 + r] = pw1[((long)co*512 + c5/5)*5 + (c5%5)]; continue; }
    r -= 1310720;
    if (r < 1310720) { int c5 = (int)(r / 512), co = (int)(r % 512); ws[OFF_PWT2 + r] = pw2[((long)co*512 + c5/5)*5 + (c5%5)]; continue; }
    r -= 1310720;
    if (r < 1310720) { int c5 = (int)(r / 512), co = (int)(r % 512); ws[OFF_PWT3 + r] = pw3[((long)co*512 + c5/5)*5 + (c5%5)]; continue; }
    r -= 1310720;
    { int c5 = (int)(r / 80), co = (int)(r % 80); ws[OFF_PWT4 + r] = pw4[((long)co*512 + c5/5)*5 + (c5%5)]; }
  }
}

// ---------------- prolog: prenet for all 500 steps ----------------
__global__ __launch_bounds__(256) void k_prenet(
    const float* __restrict__ mel_tgt, const float* __restrict__ p1b,
    const float* __restrict__ p2b, float* __restrict__ ws)
{
  int t = blockIdx.x, tid = threadIdx.x;
  const float* p1wT = ws + OFF_P1WT;
  const float* p2wT = ws + OFF_P2WT;
  __shared__ float prev_s[16][80];
  __shared__ float h1_s[16][256];
  for (int sb = 0; sb < 4; ++sb) {
    int b0 = sb * 16;
    for (int i = tid; i < 16*80; i += 256) {
      int rr = i / 80, k = i - rr*80;
      float v = 0.f;
      if (t > 0) v = mel_tgt[((long)(b0 + rr)*500 + (t-1))*80 + k];
      prev_s[rr][k] = v;
    }
    __syncthreads();
    int j = tid;
    for (int rr = 0; rr < 16; ++rr) {
      float acc = p1b[j];
      for (int k = 0; k < 80; ++k) acc = fmaf(prev_s[rr][k], p1wT[k*256 + j], acc);
      h1_s[rr][j] = fmaxf(acc, 0.f);
    }
    __syncthreads();
    for (int rr = 0; rr < 16; ++rr) {
      float acc = p2b[j];
      for (int k = 0; k < 256; ++k) acc = fmaf(h1_s[rr][k], p2wT[k*256 + j], acc);
      ws[OFF_PRE + ((long)t*64 + b0 + rr)*256 + j] = fmaxf(acc, 0.f);
    }
    __syncthreads();
  }
}

// ---------------- prolog: mem^T[b][a][te] = sum_d enc[b][te][d]*am[a][d] ----------------
// grid (8 a-chunks, 4 te-chunks, 64 b)
__global__ __launch_bounds__(256) void k_memT(
    const float* __restrict__ enc, const float* __restrict__ am, float* __restrict__ ws)
{
  int a0 = blockIdx.x * 16, te0 = blockIdx.y * 128, b = blockIdx.z;
  int tid = threadIdx.x;
  int tl = tid & 127, ah = tid >> 7;
  __shared__ float amS[16*512];
  __shared__ float encS[128][33];
  for (int i = 0; i < 32; ++i) {
    int flat = tid + i*256;
    int ar = flat >> 9, d = flat & 511;
    amS[flat] = am[(long)(a0 + ar)*512 + d];
  }
  __syncthreads();
  float acc[8];
#pragma unroll
  for (int j = 0; j < 8; ++j) acc[j] = 0.f;
  for (int d0 = 0; d0 < 512; d0 += 32) {
    for (int i = 0; i < 16; ++i) {
      int flat = tid + i*256;
      int te = flat >> 5, dd = flat & 31;
      encS[te][dd] = enc[((long)b*512 + te0 + te)*512 + d0 + dd];
    }
    __syncthreads();
#pragma unroll 4
    for (int dd = 0; dd < 32; ++dd) {
      float xv = encS[tl][dd];
#pragma unroll
      for (int j = 0; j < 8; ++j)
        acc[j] = fmaf(xv, amS[(ah*8 + j)*512 + d0 + dd], acc[j]);
    }
    __syncthreads();
  }
#pragma unroll
  for (int j = 0; j < 8; ++j)
    ws[OFF_MEM + ((long)b*128 + a0 + ah*8 + j)*512 + te0 + tl] = acc[j];
}

// ---------------- LDS pool offsets for k_decode (floats) ----------------
static constexpr int L_WL    = 0;      // 4096 persistent
static constexpr int L_AES   = 4096;   // 128  persistent
static constexpr int L_QS    = 4224;   // 128  (P1)
static constexpr int L_QPART = 4352;   // 128  (P1)
static constexpr int L_APL   = 4480;   // 160  (P1)
static constexpr int L_EPART = 4672;   // 256  (P1)
static constexpr int L_ESM   = 4224;   // 512  (P2, overlays P1 scratch)
static constexpr int L_RED   = 4736;   // 256  (P2)
static constexpr int L_HX    = 4992;   // 1536 (P2)
static constexpr int L_ENCS  = 6528;   // 4096 (P2)
static constexpr int L_XS    = 4224;   // 64*65=4160 (P3/P4, overlays P1/P2)
static constexpr int L_GSH   = 8384;   // 4*64*4=1024 (P3/P4)
static constexpr int L_POOL  = 10624;  // 42.5 KB

// ---------------- gates GEMM + fused LSTM cell (device fn) ----------------
__device__ __forceinline__ void gates_phase(
    int mode, int t, int p,
    const float* __restrict__ wih, const float* __restrict__ whh,
    float* __restrict__ ws, float* __restrict__ pool, int jt, int tid)
{
  float* xs  = pool + L_XS;    // [64][65]
  float* gsh = pool + L_GSH;   // [4][64][4]
  int bl = tid & 63;
  int g = __builtin_amdgcn_readfirstlane(tid >> 6);
  int u0 = jt * 4;
  const int K  = mode ? 2048 : 1792;
  const int KH = mode ? 1024 : 768;
  const int LD = mode ? 1024 : 768;
  const float* gb = ws + (mode ? OFF_GB1 : OFF_GB0);
  float acc0 = gb[g*1024 + u0 + 0];
  float acc1 = gb[g*1024 + u0 + 1];
  float acc2 = gb[g*1024 + u0 + 2];
  float acc3 = gb[g*1024 + u0 + 3];
  const float* srcPre = ws + OFF_PRE + (long)t*64*256;
  const float* srcCtx = ws + OFF_CTX + (long)(1 - p)*32768;
  const float* h0r = ws + OFF_H0 + (long)p*65536;
  const float* h0n = ws + OFF_H0 + (long)(1 - p)*65536;
  const float* h1r = ws + OFF_H1 + (long)p*65536;
  for (int k0 = 0; k0 < K; k0 += 64) {
#pragma unroll
    for (int i = 0; i < 16; ++i) {
      int flat = tid + i*256;
      int bb = flat >> 6, kk = flat & 63;
      int k = k0 + kk;
      float v;
      if (mode == 0) {
        if (k < 256)      v = srcPre[bb*256 + k];
        else if (k < 768) v = srcCtx[bb*512 + (k - 256)];
        else              v = h0r[bb*1024 + (k - 768)];
      } else {
        v = (k < 1024) ? h0n[bb*1024 + k] : h1r[bb*1024 + (k - 1024)];
      }
      xs[bb*65 + kk] = v;
    }
    __syncthreads();
    long jbase = (long)g*1024 + u0;
    const float* r0;
    long ld;
    if (k0 < KH) { r0 = wih + jbase*LD + k0; ld = LD; }
    else         { r0 = whh + jbase*1024 + (k0 - KH); ld = 1024; }
    const float* r1 = r0 + ld;
    const float* r2 = r1 + ld;
    const float* r3 = r2 + ld;
#pragma unroll 16
    for (int kk = 0; kk < 64; ++kk) {
      float xv = xs[bl*65 + kk];
      acc0 = fmaf(xv, r0[kk], acc0);
      acc1 = fmaf(xv, r1[kk], acc1);
      acc2 = fmaf(xv, r2[kk], acc2);
      acc3 = fmaf(xv, r3[kk], acc3);
    }
    __syncthreads();
  }
  gsh[(g*64 + bl)*4 + 0] = acc0;
  gsh[(g*64 + bl)*4 + 1] = acc1;
  gsh[(g*64 + bl)*4 + 2] = acc2;
  gsh[(g*64 + bl)*4 + 3] = acc3;
  __syncthreads();
  {
    float iv = gsh[(0*64 + bl)*4 + g];
    float fv = gsh[(1*64 + bl)*4 + g];
    float gv = gsh[(2*64 + bl)*4 + g];
    float ov = gsh[(3*64 + bl)*4 + g];
    long hw = (mode ? OFF_H1 : OFF_H0) + (long)(1 - p)*65536 + (long)bl*1024 + u0 + g;
    long cw = (mode ? OFF_C1 : OFF_C0) + (long)bl*1024 + u0 + g;
    float cold = ws[cw];
    float c2 = fsigmoid(fv)*cold + fsigmoid(iv)*ftanh(gv);
    ws[cw] = c2;
    ws[hw] = fsigmoid(ov)*ftanh(c2);
  }
}

// ---------------- the persistent cooperative decode loop ----------------
__global__ __launch_bounds__(256, 1) void k_decode(
    const float* __restrict__ enc,
    const float* __restrict__ wih0, const float* __restrict__ whh0,
    const float* __restrict__ wih1, const float* __restrict__ whh1,
    const float* __restrict__ ae,  const float* __restrict__ mbv,
    const float* __restrict__ sw,  const float* __restrict__ sb,
    float* __restrict__ dout, float* __restrict__ ws)
{
  cg::grid_group grid = cg::this_grid();
  const int bid = blockIdx.x;
  const int tid = threadIdx.x;
  const int b  = bid >> 2;   // batch
  const int qt = bid & 3;    // te/d quarter

  __shared__ float pool[L_POOL];
  for (int i = tid; i < 4096; i += 256) pool[L_WL + i] = ws[OFF_WLOC + i];
  if (tid < 128) pool[L_AES + tid] = ae[tid];
  __syncthreads();

  for (int t = 0; t <= 500; ++t) {
    const int p = t & 1;
    // ========== P1: q(t) (redundant per qt) + energy slice ==========
    if (t < 500) {
      {
        const float* h1p = ws + OFF_H1 + (long)p*65536 + (long)b*1024;
        const float* aqT = ws + OFF_AQT;
        int a = tid & 127, kh = tid >> 7;
        const float* aqp = aqT + (long)(kh*512)*128 + a;
        const float* hh  = h1p + kh*512;
        float acc = 0.f;
#pragma unroll 8
        for (int k = 0; k < 512; ++k) acc = fmaf(hh[k], aqp[(long)k*128], acc);
        if (kh) pool[L_QPART + a] = acc;
        __syncthreads();
        if (!kh) pool[L_QS + a] = acc + pool[L_QPART + a] + ws[OFF_BLOC + a];
      }
      if (tid < 160) {
        int gte = qt*128 - 15 + tid;
        float v = 0.f;
        if (t > 0 && tid < 158 && gte >= 0 && gte < 512)
          v = dout[DO_ATT + ((long)b*500 + (t-1))*512 + gte];
        pool[L_APL + tid] = v;
      }
      __syncthreads();
      {
        int tl = tid & 127, ah = tid >> 7;
        const float* memb = ws + OFF_MEM + (long)b*128*512 + qt*128;
        float e = 0.f;
        for (int a = ah*64; a < ah*64 + 64; ++a) {
          float acc = pool[L_QS + a] + memb[(long)a*512 + tl];
          const float* wl = pool + L_WL + a*32;
#pragma unroll
          for (int k = 0; k < 31; ++k) acc = fmaf(pool[L_APL + tl + k], wl[k], acc);
          e = fmaf(pool[L_AES + a], ftanh(acc), e);
        }
        pool[L_EPART + ah*128 + tl] = e;
        __syncthreads();
        if (tid < 128)
          ws[OFF_EBUF + (long)b*512 + qt*128 + tid] =
              pool[L_EPART + tid] + pool[L_EPART + 128 + tid];
      }
    }
    grid.sync();
    // ========== P2: softmax + ctx slice + heads(t-1) ==========
    {
      float* esm = pool + L_ESM;
      float* red = pool + L_RED;
      float* hx  = pool + L_HX;
      if (t < 500) {
        const float* eb = ws + OFF_EBUF + (long)b*512;
        esm[tid] = eb[tid]; esm[tid + 256] = eb[tid + 256];
      }
      if (t > 0 && qt == 0) {
        const float* h1p = ws + OFF_H1 + (long)p*65536 + (long)b*1024;
        const float* cxp = ws + OFF_CTX + (long)p*32768 + (long)b*512;
        for (int i = tid; i < 1536; i += 256)
          hx[i] = (i < 1024) ? h1p[i] : cxp[i - 1024];
      }
      __syncthreads();
      if (t < 500) {
        red[tid] = fmaxf(esm[tid], esm[tid + 256]);
        __syncthreads();
        for (int s = 128; s > 0; s >>= 1) {
          if (tid < s) red[tid] = fmaxf(red[tid], red[tid + s]);
          __syncthreads();
        }
        float mx = red[0];
        __syncthreads();
        float p0 = __expf(esm[tid] - mx), p1 = __expf(esm[tid + 256] - mx);
        red[tid] = p0 + p1;
        __syncthreads();
        for (int s = 128; s > 0; s >>= 1) {
          if (tid < s) red[tid] += red[tid + s];
          __syncthreads();
        }
        float inv = 1.f / red[0];
        __syncthreads();
        esm[tid] = p0 * inv; esm[tid + 256] = p1 * inv;
        __syncthreads();
        if (tid < 128)
          dout[DO_ATT + ((long)b*500 + t)*512 + qt*128 + tid] = esm[qt*128 + tid];
        // ctx over LDS-staged enc tiles
        const float* encb = enc + (long)b*512*512 + qt*128;
        float cacc = 0.f;
        for (int te0 = 0; te0 < 512; te0 += 32) {
#pragma unroll
          for (int i = 0; i < 16; ++i) {
            int flat = tid + i*256;
            pool[L_ENCS + flat] = encb[(long)(te0 + (flat >> 7))*512 + (flat & 127)];
          }
          __syncthreads();
          if (tid < 128) {
#pragma unroll
            for (int te = 0; te < 32; ++te)
              cacc = fmaf(esm[te0 + te], pool[L_ENCS + te*128 + tid], cacc);
          }
          __syncthreads();
        }
        if (tid < 128)
          ws[OFF_CTX + (long)(1 - p)*32768 + (long)b*512 + qt*128 + tid] = cacc;
      }
      // heads(t-1): only qt==0 block per b; mel split 240-way, stop 3-way
      if (t > 0 && qt == 0) {
        if (tid < 240) {
          int kc = tid / 80;
          int out = tid - kc*80;
          const float* mwT = ws + OFF_MWT;
          float acc = 0.f;
          int k0 = kc*512;
#pragma unroll 4
          for (int k = k0; k < k0 + 512; ++k) acc = fmaf(hx[k], mwT[k*80 + out], acc);
          red[tid] = acc;
        } else if (tid < 243) {
          int k0 = (tid - 240)*512;
          float acc = 0.f;
#pragma unroll 4
          for (int k = k0; k < k0 + 512; ++k) acc = fmaf(hx[k], sw[k], acc);
          red[tid] = acc;
        }
        __syncthreads();
        if (tid < 80)
          dout[DO_MEL + ((long)b*500 + (t-1))*80 + tid] =
              mbv[tid] + red[tid] + red[tid + 80] + red[tid + 160];
        else if (tid == 80)
          dout[DO_STOP + (long)b*500 + (t-1)] =
              sb[0] + red[240] + red[241] + red[242];
      }
    }
    grid.sync();
    if (t == 500) break;
    // ========== P3 / P4: gates + cells ==========
    gates_phase(0, t, p, wih0, whh0, ws, pool, bid, tid);
    grid.sync();
    gates_phase(1, t, p, wih1, whh1, ws, pool, bid, tid);
    grid.sync();
  }
}

// ---------------- epilog: postnet conv layer (unchanged from R1) ----------------
__global__ __launch_bounds__(256) void k_conv(
    const float* __restrict__ in, float* __restrict__ out,
    const float* __restrict__ wT, const float* __restrict__ pb,
    const float* __restrict__ bg, const float* __restrict__ bbp,
    const float* __restrict__ melp,
    int CI, int CO, int flags)
{
  int tx = blockIdx.x, cy = blockIdx.y, b = blockIdx.z;
  int tid = threadIdx.x;
  int tl = tid & 63;
  int cog = __builtin_amdgcn_readfirstlane(tid >> 6);
  int t0 = tx * 64;
  int co0 = cy*64 + cog*16;
  __shared__ float xs[16][68];
  float acc[16];
#pragma unroll
  for (int i = 0; i < 16; ++i) acc[i] = 0.f;
  for (int ci0 = 0; ci0 < CI; ci0 += 16) {
    for (int i = tid; i < 16*68; i += 256) {
      int cl = i / 68, tt = i - cl*68;
      int tg = t0 + tt - 2;
      float v = 0.f;
      if (tg >= 0 && tg < 500) {
        if (flags & 1) v = in[((long)b*500 + tg)*80 + (ci0 + cl)];
        else           v = in[((long)b*CI + ci0 + cl)*500 + tg];
      }
      xs[cl][tt] = v;
    }
    __syncthreads();
    for (int cl = 0; cl < 16; ++cl) {
#pragma unroll
      for (int k = 0; k < 5; ++k) {
        const float* wr = wT + ((long)((ci0 + cl)*5 + k))*CO + co0;
        float xv = xs[cl][tl + k];
#pragma unroll
        for (int i = 0; i < 16; ++i) acc[i] = fmaf(xv, wr[i], acc[i]);
      }
    }
    __syncthreads();
  }
  int tg = t0 + tl;
  if (tg < 500) {
    const float RS = 0.99999500003749969f;  // 1/sqrt(1+1e-5)
#pragma unroll
    for (int i = 0; i < 16; ++i) {
      int co = co0 + i;
      if (co < CO) {
        float sc = bg[co] * RS;
        float v = fmaf(acc[i], sc, fmaf(pb[co], sc, bbp[co]));
        if (flags & 4) v = ftanh(v);
        if (flags & 2) { long oi = ((long)b*500 + tg)*80 + co; out[oi] = melp[oi] + v; }
        else out[((long)b*CO + co)*500 + tg] = v;
      }
    }
  }
}

// ---------------- launch ----------------
extern "C" void kernel_launch(void* const* d_in, const int* in_sizes, int n_in,
                              void* d_out, int out_size, void* d_ws, size_t ws_size,
                              hipStream_t stream)
{
  (void)in_sizes; (void)n_in; (void)out_size; (void)ws_size;
  const float* enc     = (const float*)d_in[0];
  const float* mel_tgt = (const float*)d_in[1];
  const float* p1w = (const float*)d_in[2];
  const float* p1b = (const float*)d_in[3];
  const float* p2w = (const float*)d_in[4];
  const float* p2b = (const float*)d_in[5];
  const float* wih0 = (const float*)d_in[6];
  const float* whh0 = (const float*)d_in[7];
  const float* bih0 = (const float*)d_in[8];
  const float* bhh0 = (const float*)d_in[9];
  const float* wih1 = (const float*)d_in[10];
  const float* whh1 = (const float*)d_in[11];
  const float* bih1 = (const float*)d_in[12];
  const float* bhh1 = (const float*)d_in[13];
  const float* aq   = (const float*)d_in[14];
  const float* am   = (const float*)d_in[15];
  const float* al   = (const float*)d_in[16];
  const float* alcw = (const float*)d_in[17];
  const float* alcb = (const float*)d_in[18];
  const float* ae   = (const float*)d_in[19];
  const float* ab   = (const float*)d_in[20];
  const float* mw   = (const float*)d_in[21];
  const float* mb   = (const float*)d_in[22];
  const float* sw   = (const float*)d_in[23];
  const float* sb   = (const float*)d_in[24];
  const float* pw0 = (const float*)d_in[25];
  const float* pb0 = (const float*)d_in[26];
  const float* bg0 = (const float*)d_in[27];
  const float* bb0 = (const float*)d_in[28];
  const float* pw1 = (const float*)d_in[29];
  const float* pb1 = (const float*)d_in[30];
  const float* bg1 = (const float*)d_in[31];
  const float* bb1 = (const float*)d_in[32];
  const float* pw2 = (const float*)d_in[33];
  const float* pb2 = (const float*)d_in[34];
  const float* bg2 = (const float*)d_in[35];
  const float* bb2 = (const float*)d_in[36];
  const float* pw3 = (const float*)d_in[37];
  const float* pb3 = (const float*)d_in[38];
  const float* bg3 = (const float*)d_in[39];
  const float* bb3 = (const float*)d_in[40];
  const float* pw4 = (const float*)d_in[41];
  const float* pb4 = (const float*)d_in[42];
  const float* bg4 = (const float*)d_in[43];
  const float* bb4 = (const float*)d_in[44];

  float* ws = (float*)d_ws;
  float* dout = (float*)d_out;

  // prolog
  k_prep<<<dim3(2048), 256, 0, stream>>>(bih0, bhh0, bih1, bhh1, al, alcw, alcb, ab,
                                         p1w, p2w, mw, aq, pw0, pw1, pw2, pw3, pw4, ws);
  k_prenet<<<dim3(500), 256, 0, stream>>>(mel_tgt, p1b, p2b, ws);
  k_memT<<<dim3(8, 4, 64), 256, 0, stream>>>(enc, am, ws);

  // cooperative decode loop (500 steps inside one kernel)
  {
    void* kargs[] = {
      (void*)&enc, (void*)&wih0, (void*)&whh0, (void*)&wih1, (void*)&whh1,
      (void*)&ae, (void*)&mb, (void*)&sw, (void*)&sb, (void*)&dout, (void*)&ws
    };
    hipLaunchCooperativeKernel((const void*)k_decode, dim3(256), dim3(256),
                               kargs, 0, stream);
  }

  // postnet
  k_conv<<<dim3(8, 8, 64), 256, 0, stream>>>(dout + DO_MEL, ws + OFF_PB0, ws + OFF_PWT0,
                                             pb0, bg0, bb0, nullptr, 80, 512, 1 | 4);
  k_conv<<<dim3(8, 8, 64), 256, 0, stream>>>(ws + OFF_PB0, ws + OFF_PB1, ws + OFF_PWT1,
                                             pb1, bg1, bb1, nullptr, 512, 512, 4);
  k_conv<<<dim3(8, 8, 64), 256, 0, stream>>>(ws + OFF_PB1, ws + OFF_PB0, ws + OFF_PWT2,
                                             pb2, bg2, bb2, nullptr, 512, 512, 4);
  k_conv<<<dim3(8, 8, 64), 256, 0, stream>>>(ws + OFF_PB0, ws + OFF_PB1, ws + OFF_PWT3,
                                             pb3, bg3, bb3, nullptr, 512, 512, 4);
  k_conv<<<dim3(8, 2, 64), 256, 0, stream>>>(ws + OFF_PB1, dout, ws + OFF_PWT4,
                                             pb4, bg4, bb4, dout + DO_MEL, 512, 80, 2);
}